// Round 1
// baseline (133.950 us; speedup 1.0000x reference)
//
#include <hip/hip_runtime.h>

// Problem dims (fixed by reference): B=32, S=64, E=256, H=4, D=64
constexpr int ED = 256;    // embedding dim
constexpr int SD = 64;     // seq len
constexpr int BD = 32;     // batch
constexpr int HD = 4;      // heads
constexpr int DD = 64;     // head dim (== SD)
constexpr int NROWS = BD * SD;  // 2048 rows of (E)
constexpr int RB = 8;      // rows per block in linear kernels

// ---------------------------------------------------------------------------
// Kernel A: ET[z][j][i] = exp(W_z[i][j])  (transposed so the j-loop in the
// linear kernels reads coalesced columns). LDS 32x33 tile transpose.
// grid (8,8,4), block 256
// ---------------------------------------------------------------------------
__global__ __launch_bounds__(256) void expT_kernel(
    const float* __restrict__ W0, const float* __restrict__ W1,
    const float* __restrict__ W2, const float* __restrict__ W3,
    float* __restrict__ et_base)
{
  const float* W = (blockIdx.z == 0) ? W0 : (blockIdx.z == 1) ? W1
                 : (blockIdx.z == 2) ? W2 : W3;
  float* ET = et_base + (size_t)blockIdx.z * ED * ED;
  __shared__ float tile[32][33];
  int tx = threadIdx.x & 31, ty = threadIdx.x >> 5;   // 32 x 8
  int i0 = blockIdx.y * 32, j0 = blockIdx.x * 32;
#pragma unroll
  for (int r = 0; r < 4; r++)
    tile[ty + 8 * r][tx] = __expf(W[(i0 + ty + 8 * r) * ED + j0 + tx]);
  __syncthreads();
#pragma unroll
  for (int r = 0; r < 4; r++)
    ET[(j0 + ty + 8 * r) * ED + i0 + tx] = tile[tx][ty + 8 * r];
}

// ---------------------------------------------------------------------------
// Kernel B: per block, RB rows. Computes q,k,v tropical linears via
// M + log(expW @ exp(x-M)) + b, then fused softmax(q+k) per 64-wide head
// segment (head == wave). Writes attn (B,S,E layout = b,h? no: b,s,h*64+d)
// and v (same layout).
// grid NROWS/RB, block 256
// ---------------------------------------------------------------------------
__global__ __launch_bounds__(256) void qkv_kernel(
    const float* __restrict__ x,
    const float* __restrict__ EqT, const float* __restrict__ EkT,
    const float* __restrict__ EvT,
    const float* __restrict__ bq, const float* __restrict__ bk,
    const float* __restrict__ bv,
    float* __restrict__ attn, float* __restrict__ vout)
{
  int t = threadIdx.x;
  int lane = t & 63, wave = t >> 6;
  int row0 = blockIdx.x * RB;
  __shared__ float e[RB][ED];
  __shared__ float red[RB][4];

  float xv[RB];
#pragma unroll
  for (int r = 0; r < RB; r++) xv[r] = x[(row0 + r) * ED + t];

  // per-row max over 256 threads: wave shuffle + LDS combine
#pragma unroll
  for (int r = 0; r < RB; r++) {
    float m = xv[r];
#pragma unroll
    for (int off = 32; off > 0; off >>= 1) m = fmaxf(m, __shfl_xor(m, off));
    if (lane == 0) red[r][wave] = m;
  }
  __syncthreads();
  float M[RB];
#pragma unroll
  for (int r = 0; r < RB; r++) {
    float m = fmaxf(fmaxf(red[r][0], red[r][1]), fmaxf(red[r][2], red[r][3]));
    M[r] = m;
    e[r][t] = __expf(xv[r] - m);
  }
  __syncthreads();

  float aq[RB], ak[RB], av[RB];
#pragma unroll
  for (int r = 0; r < RB; r++) { aq[r] = 0.f; ak[r] = 0.f; av[r] = 0.f; }

  for (int j4 = 0; j4 < ED / 4; j4++) {
    float4 e4[RB];
#pragma unroll
    for (int r = 0; r < RB; r++) e4[r] = ((const float4*)e[r])[j4];  // LDS b128 broadcast
#pragma unroll
    for (int u = 0; u < 4; u++) {
      int j = j4 * 4 + u;
      float wq = EqT[j * ED + t];   // coalesced 256B/wave
      float wk = EkT[j * ED + t];
      float wv = EvT[j * ED + t];
#pragma unroll
      for (int r = 0; r < RB; r++) {
        float ej = (u == 0) ? e4[r].x : (u == 1) ? e4[r].y
                 : (u == 2) ? e4[r].z : e4[r].w;
        aq[r] = fmaf(wq, ej, aq[r]);
        ak[r] = fmaf(wk, ej, ak[r]);
        av[r] = fmaf(wv, ej, av[r]);
      }
    }
  }

  float bqv = bq[t], bkv = bk[t], bvv = bv[t];
#pragma unroll
  for (int r = 0; r < RB; r++) {
    float qv = M[r] + __logf(aq[r]) + bqv;
    float kv = M[r] + __logf(ak[r]) + bkv;
    float vv = M[r] + __logf(av[r]) + bvv;
    vout[(row0 + r) * ED + t] = vv;
    // softmax of (q+k) over the 64-lane head segment == this wave
    float s = qv + kv;
    float sm = s;
#pragma unroll
    for (int off = 32; off > 0; off >>= 1) sm = fmaxf(sm, __shfl_xor(sm, off));
    float ex = __expf(s - sm);
    float den = ex;
#pragma unroll
    for (int off = 32; off > 0; off >>= 1) den += __shfl_xor(den, off);
    attn[(row0 + r) * ED + t] = ex / den;
  }
}

// ---------------------------------------------------------------------------
// Kernel C: out[b,h,s,e'] = sum_d attn[b,h,s,d] * v[b,h,d,e']  (v's seq axis
// indexed by d since D==S). One block per (b,h). v-column in 64 regs,
// attn tile in LDS with broadcast float4 reads.
// grid B*H = 128, block 256
// ---------------------------------------------------------------------------
__global__ __launch_bounds__(256) void av_kernel(
    const float* __restrict__ attn, const float* __restrict__ vbuf,
    float* __restrict__ obuf)
{
  int b = blockIdx.x >> 2, h = blockIdx.x & 3;
  int t = threadIdx.x, lane = t & 63, wave = t >> 6;
  __shared__ float at[SD][DD];   // 16 KB
#pragma unroll
  for (int p = 0; p < 16; p++) {
    int idx = p * 256 + t;
    int s = idx >> 6, d = idx & 63;
    at[s][d] = attn[(b * SD + s) * ED + h * DD + d];
  }
  float vr[DD];
#pragma unroll
  for (int d = 0; d < DD; d++)
    vr[d] = vbuf[(b * SD + d) * ED + h * DD + lane];   // coalesced per d
  __syncthreads();
#pragma unroll
  for (int p = 0; p < 16; p++) {
    int s = wave * 16 + p;   // same s across the wave -> LDS broadcast reads
    const float4* arow = (const float4*)at[s];
    float acc = 0.f;
#pragma unroll
    for (int d4 = 0; d4 < 16; d4++) {
      float4 a4 = arow[d4];
      acc = fmaf(a4.x, vr[4 * d4 + 0], acc);
      acc = fmaf(a4.y, vr[4 * d4 + 1], acc);
      acc = fmaf(a4.z, vr[4 * d4 + 2], acc);
      acc = fmaf(a4.w, vr[4 * d4 + 3], acc);
    }
    obuf[(b * SD + s) * ED + h * DD + lane] = acc;
  }
}

// ---------------------------------------------------------------------------
// Kernel D: final tropical linear (Wo, bo) on obuf rows -> d_out.
// Same structure as qkv_kernel but single matrix.
// grid NROWS/RB, block 256
// ---------------------------------------------------------------------------
__global__ __launch_bounds__(256) void o_kernel(
    const float* __restrict__ inp, const float* __restrict__ EoT,
    const float* __restrict__ bo, float* __restrict__ y)
{
  int t = threadIdx.x;
  int lane = t & 63, wave = t >> 6;
  int row0 = blockIdx.x * RB;
  __shared__ float e[RB][ED];
  __shared__ float red[RB][4];

  float xv[RB];
#pragma unroll
  for (int r = 0; r < RB; r++) xv[r] = inp[(row0 + r) * ED + t];
#pragma unroll
  for (int r = 0; r < RB; r++) {
    float m = xv[r];
#pragma unroll
    for (int off = 32; off > 0; off >>= 1) m = fmaxf(m, __shfl_xor(m, off));
    if (lane == 0) red[r][wave] = m;
  }
  __syncthreads();
  float M[RB];
#pragma unroll
  for (int r = 0; r < RB; r++) {
    float m = fmaxf(fmaxf(red[r][0], red[r][1]), fmaxf(red[r][2], red[r][3]));
    M[r] = m;
    e[r][t] = __expf(xv[r] - m);
  }
  __syncthreads();

  float acc[RB];
#pragma unroll
  for (int r = 0; r < RB; r++) acc[r] = 0.f;
  for (int j4 = 0; j4 < ED / 4; j4++) {
    float4 e4[RB];
#pragma unroll
    for (int r = 0; r < RB; r++) e4[r] = ((const float4*)e[r])[j4];
#pragma unroll
    for (int u = 0; u < 4; u++) {
      int j = j4 * 4 + u;
      float w = EoT[j * ED + t];
#pragma unroll
      for (int r = 0; r < RB; r++) {
        float ej = (u == 0) ? e4[r].x : (u == 1) ? e4[r].y
                 : (u == 2) ? e4[r].z : e4[r].w;
        acc[r] = fmaf(w, ej, acc[r]);
      }
    }
  }
  float bov = bo[t];
#pragma unroll
  for (int r = 0; r < RB; r++)
    y[(row0 + r) * ED + t] = M[r] + __logf(acc[r]) + bov;
}

// ---------------------------------------------------------------------------
extern "C" void kernel_launch(void* const* d_in, const int* in_sizes, int n_in,
                              void* d_out, int out_size, void* d_ws, size_t ws_size,
                              hipStream_t stream) {
  const float* x  = (const float*)d_in[0];
  const float* Wq = (const float*)d_in[1];
  const float* bq = (const float*)d_in[2];
  const float* Wk = (const float*)d_in[3];
  const float* bk = (const float*)d_in[4];
  const float* Wv = (const float*)d_in[5];
  const float* bv = (const float*)d_in[6];
  const float* Wo = (const float*)d_in[7];
  const float* bo = (const float*)d_in[8];
  float* y = (float*)d_out;

  // workspace layout (floats): 4x EwT (1 MB) + attn + v + o (6 MB) = 7 MB
  float* ws   = (float*)d_ws;
  float* EqT  = ws;
  float* EkT  = EqT + ED * ED;
  float* EvT  = EkT + ED * ED;
  float* EoT  = EvT + ED * ED;
  float* attn = EoT + ED * ED;
  float* vbuf = attn + NROWS * ED;
  float* obuf = vbuf + NROWS * ED;

  expT_kernel<<<dim3(8, 8, 4), 256, 0, stream>>>(Wq, Wk, Wv, Wo, EqT);
  qkv_kernel<<<NROWS / RB, 256, 0, stream>>>(x, EqT, EkT, EvT, bq, bk, bv,
                                             attn, vbuf);
  av_kernel<<<BD * HD, 256, 0, stream>>>(attn, vbuf, obuf);
  o_kernel<<<NROWS / RB, 256, 0, stream>>>(obuf, EoT, bo, y);
}

// Round 2
// 101.083 us; speedup vs baseline: 1.3251x; 1.3251x over previous
//
#include <hip/hip_runtime.h>

// Problem dims (fixed by reference): B=32, S=64, E=256, H=4, D=64
constexpr int ED = 256;    // embedding dim
constexpr int SD = 64;     // seq len
constexpr int BD = 32;     // batch
constexpr int HD = 4;      // heads
constexpr int DD = 64;     // head dim (== SD)
constexpr int NROWS = BD * SD;  // 2048 rows of (E)
constexpr int RB = 8;      // rows per block in linear kernels

// ---------------------------------------------------------------------------
// Kernel A: ET[z][j][i] = exp(W_z[i][j]) (transposed so the j-loop in the
// linear kernels reads coalesced). LDS 32x33 tile transpose.
// grid (8,8,4), block 256
// ---------------------------------------------------------------------------
__global__ __launch_bounds__(256) void expT_kernel(
    const float* __restrict__ W0, const float* __restrict__ W1,
    const float* __restrict__ W2, const float* __restrict__ W3,
    float* __restrict__ et_base)
{
  const float* W = (blockIdx.z == 0) ? W0 : (blockIdx.z == 1) ? W1
                 : (blockIdx.z == 2) ? W2 : W3;
  float* ET = et_base + (size_t)blockIdx.z * ED * ED;
  __shared__ float tile[32][33];
  int tx = threadIdx.x & 31, ty = threadIdx.x >> 5;   // 32 x 8
  int i0 = blockIdx.y * 32, j0 = blockIdx.x * 32;
#pragma unroll
  for (int r = 0; r < 4; r++)
    tile[ty + 8 * r][tx] = __expf(W[(i0 + ty + 8 * r) * ED + j0 + tx]);
  __syncthreads();
#pragma unroll
  for (int r = 0; r < 4; r++)
    ET[(j0 + ty + 8 * r) * ED + i0 + tx] = tile[tx][ty + 8 * r];
}

// ---------------------------------------------------------------------------
// Kernel B: RB rows per block, block = 1024 threads (16 waves, 4 waves/SIMD).
// j-dimension split 4 ways across thread groups of 256; partials reduced via
// a 32KB LDS buffer (3 sequential rounds, one per matrix). Then the owner
// threads (group g owns rows 2g,2g+1) apply M + log(.) + b and the fused
// 64-wide softmax(q+k) (head segment == wave). grid NROWS/RB = 256.
// ---------------------------------------------------------------------------
__global__ __launch_bounds__(1024) void qkv_kernel(
    const float* __restrict__ x,
    const float* __restrict__ EqT, const float* __restrict__ EkT,
    const float* __restrict__ EvT,
    const float* __restrict__ bq, const float* __restrict__ bk,
    const float* __restrict__ bv,
    float* __restrict__ attn, float* __restrict__ vout)
{
  int tid = threadIdx.x;
  int wv = tid >> 6, lane = tid & 63;
  int g = tid >> 8, t = tid & 255;           // j-group, output column
  int row0 = blockIdx.x * RB;

  __shared__ float e[RB][ED];                // 8 KB
  __shared__ float part[4][RB][ED];          // 32 KB, reused per matrix
  __shared__ float Mrow[RB];

  // --- e = exp(x - rowmax), one wave per row (waves 0..7) ---
  if (wv < RB) {
    int r = wv;
    const float* xr = x + (size_t)(row0 + r) * ED;
    float v0 = xr[lane], v1 = xr[lane + 64], v2 = xr[lane + 128], v3 = xr[lane + 192];
    float m = fmaxf(fmaxf(v0, v1), fmaxf(v2, v3));
#pragma unroll
    for (int off = 32; off > 0; off >>= 1) m = fmaxf(m, __shfl_xor(m, off));
    e[r][lane]       = __expf(v0 - m);
    e[r][lane + 64]  = __expf(v1 - m);
    e[r][lane + 128] = __expf(v2 - m);
    e[r][lane + 192] = __expf(v3 - m);
    if (lane == 0) Mrow[r] = m;
  }
  __syncthreads();

  // --- partial matmul over this group's 64 j values ---
  float aq[RB], ak[RB], av_[RB];
#pragma unroll
  for (int r = 0; r < RB; r++) { aq[r] = 0.f; ak[r] = 0.f; av_[r] = 0.f; }

  for (int j4 = 0; j4 < 16; j4++) {
    float4 e4[RB];
#pragma unroll
    for (int r = 0; r < RB; r++)
      e4[r] = ((const float4*)e[r])[16 * g + j4];   // LDS b128 broadcast
#pragma unroll
    for (int u = 0; u < 4; u++) {
      int j = 64 * g + 4 * j4 + u;
      float wq = EqT[j * ED + t];   // coalesced 256B/wave, L2-resident
      float wk = EkT[j * ED + t];
      float wvv = EvT[j * ED + t];
#pragma unroll
      for (int r = 0; r < RB; r++) {
        float ej = (u == 0) ? e4[r].x : (u == 1) ? e4[r].y
                 : (u == 2) ? e4[r].z : e4[r].w;
        aq[r]  = fmaf(wq,  ej, aq[r]);
        ak[r]  = fmaf(wk,  ej, ak[r]);
        av_[r] = fmaf(wvv, ej, av_[r]);
      }
    }
  }

  // --- cross-group reduction through LDS, 3 rounds (q, k, v) ---
  int r0 = 2 * g, r1 = 2 * g + 1;
  float fq0, fq1, fk0, fk1, fv0, fv1;

#pragma unroll
  for (int r = 0; r < RB; r++) part[g][r][t] = aq[r];
  __syncthreads();
  fq0 = part[0][r0][t] + part[1][r0][t] + part[2][r0][t] + part[3][r0][t];
  fq1 = part[0][r1][t] + part[1][r1][t] + part[2][r1][t] + part[3][r1][t];
  __syncthreads();
#pragma unroll
  for (int r = 0; r < RB; r++) part[g][r][t] = ak[r];
  __syncthreads();
  fk0 = part[0][r0][t] + part[1][r0][t] + part[2][r0][t] + part[3][r0][t];
  fk1 = part[0][r1][t] + part[1][r1][t] + part[2][r1][t] + part[3][r1][t];
  __syncthreads();
#pragma unroll
  for (int r = 0; r < RB; r++) part[g][r][t] = av_[r];
  __syncthreads();
  fv0 = part[0][r0][t] + part[1][r0][t] + part[2][r0][t] + part[3][r0][t];
  fv1 = part[0][r1][t] + part[1][r1][t] + part[2][r1][t] + part[3][r1][t];

  // --- epilogue: log, bias, v store, fused softmax(q+k) per 64-lane head ---
  float bqv = bq[t], bkv = bk[t], bvv = bv[t];
  float M0 = Mrow[r0], M1 = Mrow[r1];

#pragma unroll
  for (int rr = 0; rr < 2; rr++) {
    int r = (rr == 0) ? r0 : r1;
    float M = (rr == 0) ? M0 : M1;
    float fq = (rr == 0) ? fq0 : fq1;
    float fk = (rr == 0) ? fk0 : fk1;
    float fv = (rr == 0) ? fv0 : fv1;
    float qv = M + __logf(fq) + bqv;
    float kv = M + __logf(fk) + bkv;
    float vv = M + __logf(fv) + bvv;
    vout[(size_t)(row0 + r) * ED + t] = vv;
    float s = qv + kv;
    float sm = s;
#pragma unroll
    for (int off = 32; off > 0; off >>= 1) sm = fmaxf(sm, __shfl_xor(sm, off));
    float ex = __expf(s - sm);
    float den = ex;
#pragma unroll
    for (int off = 32; off > 0; off >>= 1) den += __shfl_xor(den, off);
    attn[(size_t)(row0 + r) * ED + t] = ex / den;
  }
}

// ---------------------------------------------------------------------------
// Kernel C: out[b,s,h*64+e'] = sum_d attn[b,s,h*64+d] * v[b,d,h*64+e'].
// One block per (b,h,s-quarter): 512 blocks (2 blocks/CU), block 256.
// v-column in 64 regs, attn tile in LDS with broadcast float4 reads.
// ---------------------------------------------------------------------------
__global__ __launch_bounds__(256) void av_kernel(
    const float* __restrict__ attn, const float* __restrict__ vbuf,
    float* __restrict__ obuf)
{
  int bh = blockIdx.x >> 2, qtr = blockIdx.x & 3;
  int b = bh >> 2, h = bh & 3;
  int t = threadIdx.x, lane = t & 63, wv = t >> 6;
  int s0 = qtr * 16;
  __shared__ float at[16][DD];   // 4 KB
#pragma unroll
  for (int p = 0; p < 4; p++) {
    int idx = p * 256 + t;
    int s = idx >> 6, d = idx & 63;
    at[s][d] = attn[(size_t)(b * SD + s0 + s) * ED + h * DD + d];
  }
  float vr[DD];
#pragma unroll
  for (int d = 0; d < DD; d++)
    vr[d] = vbuf[(size_t)(b * SD + d) * ED + h * DD + lane];   // coalesced per d
  __syncthreads();
#pragma unroll
  for (int p = 0; p < 4; p++) {
    int sl = wv * 4 + p;   // same s across the wave -> LDS broadcast reads
    const float4* arow = (const float4*)at[sl];
    float acc = 0.f;
#pragma unroll
    for (int d4 = 0; d4 < 16; d4++) {
      float4 a4 = arow[d4];
      acc = fmaf(a4.x, vr[4 * d4 + 0], acc);
      acc = fmaf(a4.y, vr[4 * d4 + 1], acc);
      acc = fmaf(a4.z, vr[4 * d4 + 2], acc);
      acc = fmaf(a4.w, vr[4 * d4 + 3], acc);
    }
    obuf[(size_t)(b * SD + s0 + sl) * ED + h * DD + lane] = acc;
  }
}

// ---------------------------------------------------------------------------
// Kernel D: final tropical linear (Wo, bo). Same 1024-thread j-split
// structure as qkv_kernel, single matrix. grid NROWS/RB = 256.
// ---------------------------------------------------------------------------
__global__ __launch_bounds__(1024) void o_kernel(
    const float* __restrict__ inp, const float* __restrict__ EoT,
    const float* __restrict__ bo, float* __restrict__ y)
{
  int tid = threadIdx.x;
  int wv = tid >> 6, lane = tid & 63;
  int g = tid >> 8, t = tid & 255;
  int row0 = blockIdx.x * RB;

  __shared__ float e[RB][ED];
  __shared__ float part[4][RB][ED];
  __shared__ float Mrow[RB];

  if (wv < RB) {
    int r = wv;
    const float* xr = inp + (size_t)(row0 + r) * ED;
    float v0 = xr[lane], v1 = xr[lane + 64], v2 = xr[lane + 128], v3 = xr[lane + 192];
    float m = fmaxf(fmaxf(v0, v1), fmaxf(v2, v3));
#pragma unroll
    for (int off = 32; off > 0; off >>= 1) m = fmaxf(m, __shfl_xor(m, off));
    e[r][lane]       = __expf(v0 - m);
    e[r][lane + 64]  = __expf(v1 - m);
    e[r][lane + 128] = __expf(v2 - m);
    e[r][lane + 192] = __expf(v3 - m);
    if (lane == 0) Mrow[r] = m;
  }
  __syncthreads();

  float acc[RB];
#pragma unroll
  for (int r = 0; r < RB; r++) acc[r] = 0.f;

  for (int j4 = 0; j4 < 16; j4++) {
    float4 e4[RB];
#pragma unroll
    for (int r = 0; r < RB; r++)
      e4[r] = ((const float4*)e[r])[16 * g + j4];
#pragma unroll
    for (int u = 0; u < 4; u++) {
      int j = 64 * g + 4 * j4 + u;
      float w = EoT[j * ED + t];
#pragma unroll
      for (int r = 0; r < RB; r++) {
        float ej = (u == 0) ? e4[r].x : (u == 1) ? e4[r].y
                 : (u == 2) ? e4[r].z : e4[r].w;
        acc[r] = fmaf(w, ej, acc[r]);
      }
    }
  }

  int r0 = 2 * g, r1 = 2 * g + 1;
#pragma unroll
  for (int r = 0; r < RB; r++) part[g][r][t] = acc[r];
  __syncthreads();
  float f0 = part[0][r0][t] + part[1][r0][t] + part[2][r0][t] + part[3][r0][t];
  float f1 = part[0][r1][t] + part[1][r1][t] + part[2][r1][t] + part[3][r1][t];

  float bov = bo[t];
  y[(size_t)(row0 + r0) * ED + t] = Mrow[r0] + __logf(f0) + bov;
  y[(size_t)(row0 + r1) * ED + t] = Mrow[r1] + __logf(f1) + bov;
}

// ---------------------------------------------------------------------------
extern "C" void kernel_launch(void* const* d_in, const int* in_sizes, int n_in,
                              void* d_out, int out_size, void* d_ws, size_t ws_size,
                              hipStream_t stream) {
  const float* x  = (const float*)d_in[0];
  const float* Wq = (const float*)d_in[1];
  const float* bq = (const float*)d_in[2];
  const float* Wk = (const float*)d_in[3];
  const float* bk = (const float*)d_in[4];
  const float* Wv = (const float*)d_in[5];
  const float* bv = (const float*)d_in[6];
  const float* Wo = (const float*)d_in[7];
  const float* bo = (const float*)d_in[8];
  float* y = (float*)d_out;

  // workspace layout (floats): 4x EwT (1 MB) + attn + v + o (6 MB) = 7 MB
  float* ws   = (float*)d_ws;
  float* EqT  = ws;
  float* EkT  = EqT + ED * ED;
  float* EvT  = EkT + ED * ED;
  float* EoT  = EvT + ED * ED;
  float* attn = EoT + ED * ED;
  float* vbuf = attn + NROWS * ED;
  float* obuf = vbuf + NROWS * ED;

  expT_kernel<<<dim3(8, 8, 4), 256, 0, stream>>>(Wq, Wk, Wv, Wo, EqT);
  qkv_kernel<<<NROWS / RB, 1024, 0, stream>>>(x, EqT, EkT, EvT, bq, bk, bv,
                                              attn, vbuf);
  av_kernel<<<BD * HD * 4, 256, 0, stream>>>(attn, vbuf, obuf);
  o_kernel<<<NROWS / RB, 1024, 0, stream>>>(obuf, EoT, bo, y);
}

// Round 3
// 98.716 us; speedup vs baseline: 1.3569x; 1.0240x over previous
//
#include <hip/hip_runtime.h>

// Problem dims (fixed by reference): B=32, S=64, E=256, H=4, D=64
constexpr int ED = 256;    // embedding dim
constexpr int SD = 64;     // seq len
constexpr int BD = 32;     // batch
constexpr int NROWS = BD * SD;  // 2048 rows of (E)
constexpr int RB = 4;      // rows per block in linear kernels -> 512 blocks

__device__ inline unsigned short f2bf(float f) {   // RNE fp32 -> bf16
  unsigned u = __float_as_uint(f);
  return (unsigned short)((u + 0x7fffu + ((u >> 16) & 1u)) >> 16);
}
__device__ inline float bf2f(unsigned short b) {
  return __uint_as_float(((unsigned)b) << 16);
}

// ---------------------------------------------------------------------------
// Kernel A: transposed exp(W) in bf16. z=0: EqkT[j][i] = pack(bf16 expWk^T,
// bf16 expWq^T) as uint32 (q low, k high). z=1: EvT/EoT ushort.
// grid (8,8,2), block 256.
// ---------------------------------------------------------------------------
__global__ __launch_bounds__(256) void expT_pack_kernel(
    const float* __restrict__ Wq, const float* __restrict__ Wk,
    const float* __restrict__ Wv, const float* __restrict__ Wo,
    unsigned int* __restrict__ EqkT, unsigned short* __restrict__ EvT,
    unsigned short* __restrict__ EoT)
{
  __shared__ float ta[32][33], tb[32][33];
  int tx = threadIdx.x & 31, ty = threadIdx.x >> 5;   // 32 x 8
  int i0 = blockIdx.y * 32, j0 = blockIdx.x * 32;
  const float* A = blockIdx.z ? Wv : Wq;
  const float* Bm = blockIdx.z ? Wo : Wk;
#pragma unroll
  for (int r = 0; r < 4; r++) {
    ta[ty + 8 * r][tx] = __expf(A [(i0 + ty + 8 * r) * ED + j0 + tx]);
    tb[ty + 8 * r][tx] = __expf(Bm[(i0 + ty + 8 * r) * ED + j0 + tx]);
  }
  __syncthreads();
  if (blockIdx.z == 0) {
#pragma unroll
    for (int r = 0; r < 4; r++)
      EqkT[(j0 + ty + 8 * r) * ED + i0 + tx] =
          ((unsigned)f2bf(tb[tx][ty + 8 * r]) << 16) | f2bf(ta[tx][ty + 8 * r]);
  } else {
#pragma unroll
    for (int r = 0; r < 4; r++) {
      EvT[(j0 + ty + 8 * r) * ED + i0 + tx] = f2bf(ta[tx][ty + 8 * r]);
      EoT[(j0 + ty + 8 * r) * ED + i0 + tx] = f2bf(tb[tx][ty + 8 * r]);
    }
  }
}

// ---------------------------------------------------------------------------
// Kernel B: q,k,v tropical linears + fused softmax(q+k). RB=4 rows/block,
// 512 blocks x 1024 threads (2 blocks/CU co-resident, 8 waves/SIMD).
// Group g (256 threads) handles j in [64g, 64g+64); single-round LDS
// reduction; group g owns row g's epilogue.
// ---------------------------------------------------------------------------
__global__ __launch_bounds__(1024, 8) void qkv_kernel(
    const float* __restrict__ x,
    const unsigned int* __restrict__ EqkT, const unsigned short* __restrict__ EvT,
    const float* __restrict__ bq, const float* __restrict__ bk,
    const float* __restrict__ bv,
    float* __restrict__ attn, float* __restrict__ vout)
{
  int tid = threadIdx.x;
  int wv = tid >> 6, lane = tid & 63;
  int g = tid >> 8, t = tid & 255;           // j-group, output column
  int row0 = blockIdx.x * RB;

  __shared__ float eT[ED][RB];               // 4 KB, eT[j][r]
  __shared__ float part[3][RB][ED][4];       // 48 KB, [mat][row][col][group]
  __shared__ float red[RB][4];

  // --- prologue: e = exp(x - rowmax); 16 waves <-> (row, 64-col segment) ---
  {
    int pr = wv & 3, ps = wv >> 2;
    float xv = x[(size_t)(row0 + pr) * ED + ps * 64 + lane];
    float m = xv;
#pragma unroll
    for (int off = 32; off > 0; off >>= 1) m = fmaxf(m, __shfl_xor(m, off));
    if (lane == 0) red[pr][ps] = m;
    __syncthreads();
    float M = fmaxf(fmaxf(red[pr][0], red[pr][1]), fmaxf(red[pr][2], red[pr][3]));
    eT[ps * 64 + lane][pr] = __expf(xv - M);
  }
  __syncthreads();

  // --- main loop: 64 j per group; 1 dword + 1 ushort load, 12 FMA per j ---
  float aq[RB] = {0, 0, 0, 0}, ak[RB] = {0, 0, 0, 0}, av_[RB] = {0, 0, 0, 0};
  const unsigned int*  pqk = EqkT + (size_t)(64 * g) * ED + t;
  const unsigned short* pv = EvT + (size_t)(64 * g) * ED + t;
#pragma unroll 4
  for (int j = 0; j < 64; ++j) {
    float4 e4 = *(const float4*)eT[64 * g + j];     // broadcast: 4 rows' e_j
    unsigned int wqk = pqk[j * ED];                 // coalesced 256B/wave
    float wvv = bf2f(pv[j * ED]);
    float wq = __uint_as_float(wqk << 16);
    float wk = __uint_as_float(wqk & 0xffff0000u);
    aq[0] = fmaf(wq, e4.x, aq[0]);  ak[0] = fmaf(wk, e4.x, ak[0]);  av_[0] = fmaf(wvv, e4.x, av_[0]);
    aq[1] = fmaf(wq, e4.y, aq[1]);  ak[1] = fmaf(wk, e4.y, ak[1]);  av_[1] = fmaf(wvv, e4.y, av_[1]);
    aq[2] = fmaf(wq, e4.z, aq[2]);  ak[2] = fmaf(wk, e4.z, ak[2]);  av_[2] = fmaf(wvv, e4.z, av_[2]);
    aq[3] = fmaf(wq, e4.w, aq[3]);  ak[3] = fmaf(wk, e4.w, ak[3]);  av_[3] = fmaf(wvv, e4.w, av_[3]);
  }

  // --- single-round cross-group reduction ---
#pragma unroll
  for (int r = 0; r < RB; r++) {
    part[0][r][t][g] = aq[r];
    part[1][r][t][g] = ak[r];
    part[2][r][t][g] = av_[r];
  }
  __syncthreads();

  // --- epilogue: group g owns row g ---
  float4 q4 = *(const float4*)part[0][g][t];
  float4 k4 = *(const float4*)part[1][g][t];
  float4 v4 = *(const float4*)part[2][g][t];
  float fq = (q4.x + q4.y) + (q4.z + q4.w);
  float fk = (k4.x + k4.y) + (k4.z + k4.w);
  float fv = (v4.x + v4.y) + (v4.z + v4.w);
  float Mr = fmaxf(fmaxf(red[g][0], red[g][1]), fmaxf(red[g][2], red[g][3]));
  float qv = Mr + __logf(fq) + bq[t];
  float kv = Mr + __logf(fk) + bk[t];
  float vv = Mr + __logf(fv) + bv[t];
  vout[(size_t)(row0 + g) * ED + t] = vv;
  // softmax of q+k over 64-lane head segment (wave == head within group)
  float s = qv + kv;
  float sm = s;
#pragma unroll
  for (int off = 32; off > 0; off >>= 1) sm = fmaxf(sm, __shfl_xor(sm, off));
  float ex = __expf(s - sm);
  float den = ex;
#pragma unroll
  for (int off = 32; off > 0; off >>= 1) den += __shfl_xor(den, off);
  attn[(size_t)(row0 + g) * ED + t] = ex / den;
}

// ---------------------------------------------------------------------------
// Kernel C: fused attn@v + output tropical linear. RB=4 rows/block,
// 512 blocks x 1024 threads. Group g: splits d 4-way for attn@v, then
// splits j 4-way for the o-linear; owns row g's epilogues.
// ---------------------------------------------------------------------------
__global__ __launch_bounds__(1024, 8) void avo_kernel(
    const float* __restrict__ attn, const float* __restrict__ vbuf,
    const unsigned short* __restrict__ EoT, const float* __restrict__ bo,
    float* __restrict__ y)
{
  int tid = threadIdx.x;
  int wv = tid >> 6, lane = tid & 63;
  int g = tid >> 8, t = tid & 255;
  int b = blockIdx.x >> 4;
  int row0 = b * SD + (blockIdx.x & 15) * RB;

  __shared__ float att[RB][ED];        // 4 KB
  __shared__ float part[RB][ED][4];    // 16 KB
  __shared__ float eoT[ED][RB];        // 4 KB
  __shared__ float red[RB][4];

  // attn rows -> LDS (1 load/thread); v columns -> 16 regs (coalesced)
  att[g][t] = attn[(size_t)(row0 + g) * ED + t];
  float vr[16];
#pragma unroll
  for (int d = 0; d < 16; ++d)
    vr[d] = vbuf[(size_t)(b * SD + 16 * g + d) * ED + t];
  __syncthreads();

  // attn @ v : out[r][t] = sum_d att[r][h*64+d] * v[d][t], d split by g
  int h64 = (t >> 6) << 6;
  float acc[RB];
#pragma unroll
  for (int r = 0; r < RB; ++r) {
    const float4* ap = (const float4*)&att[r][h64 + 16 * g];  // broadcast
    float a = 0.f;
#pragma unroll
    for (int d4 = 0; d4 < 4; ++d4) {
      float4 a4 = ap[d4];
      a = fmaf(a4.x, vr[4 * d4 + 0], a);
      a = fmaf(a4.y, vr[4 * d4 + 1], a);
      a = fmaf(a4.z, vr[4 * d4 + 2], a);
      a = fmaf(a4.w, vr[4 * d4 + 3], a);
    }
    acc[r] = a;
  }
#pragma unroll
  for (int r = 0; r < RB; ++r) part[r][t][g] = acc[r];
  __syncthreads();

  // owner: o-row value, rowmax over group, e = exp(o - M) into eoT
  float4 p4 = *(const float4*)part[g][t];
  float orow = (p4.x + p4.y) + (p4.z + p4.w);
  float m = orow;
#pragma unroll
  for (int off = 32; off > 0; off >>= 1) m = fmaxf(m, __shfl_xor(m, off));
  if (lane == 0) red[g][wv & 3] = m;
  __syncthreads();
  float M = fmaxf(fmaxf(red[g][0], red[g][1]), fmaxf(red[g][2], red[g][3]));
  eoT[t][g] = __expf(orow - M);
  __syncthreads();

  // o-linear: 64 j per group, 1 ushort load + 4 FMA per j
  float acc2[RB] = {0, 0, 0, 0};
  const unsigned short* po = EoT + (size_t)(64 * g) * ED + t;
#pragma unroll 4
  for (int j = 0; j < 64; ++j) {
    float4 e4 = *(const float4*)eoT[64 * g + j];
    float wo = bf2f(po[j * ED]);
    acc2[0] = fmaf(wo, e4.x, acc2[0]);
    acc2[1] = fmaf(wo, e4.y, acc2[1]);
    acc2[2] = fmaf(wo, e4.z, acc2[2]);
    acc2[3] = fmaf(wo, e4.w, acc2[3]);
  }
  __syncthreads();   // part reuse
#pragma unroll
  for (int r = 0; r < RB; ++r) part[r][t][g] = acc2[r];
  __syncthreads();

  float4 f4 = *(const float4*)part[g][t];
  float f = (f4.x + f4.y) + (f4.z + f4.w);
  y[(size_t)(row0 + g) * ED + t] = M + __logf(f) + bo[t];
}

// ---------------------------------------------------------------------------
extern "C" void kernel_launch(void* const* d_in, const int* in_sizes, int n_in,
                              void* d_out, int out_size, void* d_ws, size_t ws_size,
                              hipStream_t stream) {
  const float* x  = (const float*)d_in[0];
  const float* Wq = (const float*)d_in[1];
  const float* bq = (const float*)d_in[2];
  const float* Wk = (const float*)d_in[3];
  const float* bk = (const float*)d_in[4];
  const float* Wv = (const float*)d_in[5];
  const float* bv = (const float*)d_in[6];
  const float* Wo = (const float*)d_in[7];
  const float* bo = (const float*)d_in[8];
  float* y = (float*)d_out;

  // workspace layout (bytes): EqkT 256K | EvT 128K | EoT 128K | attn 2M | v 2M
  char* ws = (char*)d_ws;
  unsigned int*   EqkT = (unsigned int*)(ws);
  unsigned short* EvT  = (unsigned short*)(ws + 262144);
  unsigned short* EoT  = (unsigned short*)(ws + 393216);
  float* attn = (float*)(ws + 524288);
  float* vbuf = (float*)(ws + 524288 + (size_t)NROWS * ED * 4);

  expT_pack_kernel<<<dim3(8, 8, 2), 256, 0, stream>>>(Wq, Wk, Wv, Wo,
                                                      EqkT, EvT, EoT);
  qkv_kernel<<<NROWS / RB, 1024, 0, stream>>>(x, EqkT, EvT, bq, bk, bv,
                                              attn, vbuf);
  avo_kernel<<<NROWS / RB, 1024, 0, stream>>>(attn, vbuf, EoT, bo, y);
}

// Round 4
// 96.043 us; speedup vs baseline: 1.3947x; 1.0278x over previous
//
#include <hip/hip_runtime.h>

// Problem dims (fixed by reference): B=32, S=64, E=256, H=4, D=64
constexpr int ED = 256;    // embedding dim
constexpr int SD = 64;     // seq len
constexpr int BD = 32;     // batch
constexpr int NROWS = BD * SD;  // 2048 rows of (E)
constexpr int RB = 4;      // rows per block in avo -> 512 blocks

typedef short short8 __attribute__((ext_vector_type(8)));
typedef float floatx4 __attribute__((ext_vector_type(4)));

__device__ inline unsigned short f2bf(float f) {   // RNE fp32 -> bf16
  unsigned u = __float_as_uint(f);
  return (unsigned short)((u + 0x7fffu + ((u >> 16) & 1u)) >> 16);
}
__device__ inline float bf2f(unsigned short b) {
  return __uint_as_float(((unsigned)b) << 16);
}

// ---------------------------------------------------------------------------
// Kernel A1: B-fragment-swizzled bf16 exp(W) for q,k,v.
// B[k][n] = exp(W[n][k]); fragment layout for mfma_f32_16x16x32_bf16:
// ushort idx = ((kk*256 + n)*4 + q)*8 + jj  with k = 32*kk + 8*q + jj.
// Thread t of an 8-row n-tile: n = bx*8 + (t>>5), k = 32*kk + (t&31)
//   -> write idx = (kk*256+n)*32 + (t&31): fully coalesced. grid (32,3).
// ---------------------------------------------------------------------------
__global__ __launch_bounds__(256) void expT_swz_kernel(
    const float* __restrict__ Wq, const float* __restrict__ Wk,
    const float* __restrict__ Wv,
    unsigned short* __restrict__ EqS, unsigned short* __restrict__ EkS,
    unsigned short* __restrict__ EvS)
{
  int z = blockIdx.y;
  const float* W = (z == 0) ? Wq : (z == 1) ? Wk : Wv;
  unsigned short* out = (z == 0) ? EqS : (z == 1) ? EkS : EvS;
  int t = threadIdx.x;
  int n = blockIdx.x * 8 + (t >> 5), kl = t & 31;
#pragma unroll
  for (int kk = 0; kk < 8; ++kk) {
    float v = __expf(W[n * ED + 32 * kk + kl]);
    out[(kk * 256 + n) * 32 + kl] = f2bf(v);
  }
}

// ---------------------------------------------------------------------------
// Kernel A2: EoT[j][i] = bf16 exp(Wo[i][j]) (plain transposed layout for the
// VALU avo kernel). LDS 32x33 tile transpose. grid (8,8).
// ---------------------------------------------------------------------------
__global__ __launch_bounds__(256) void expT_o_kernel(
    const float* __restrict__ Wo, unsigned short* __restrict__ EoT)
{
  __shared__ float ta[32][33];
  int tx = threadIdx.x & 31, ty = threadIdx.x >> 5;   // 32 x 8
  int i0 = blockIdx.y * 32, j0 = blockIdx.x * 32;
#pragma unroll
  for (int r = 0; r < 4; r++)
    ta[ty + 8 * r][tx] = __expf(Wo[(i0 + ty + 8 * r) * ED + j0 + tx]);
  __syncthreads();
#pragma unroll
  for (int r = 0; r < 4; r++)
    EoT[(j0 + ty + 8 * r) * ED + i0 + tx] = f2bf(ta[tx][ty + 8 * r]);
}

// ---------------------------------------------------------------------------
// Kernel B: MFMA qkv. Block = 256 threads (4 waves) = M-tile 16 rows x
// N-tile 64 cols (one head). grid 512 = (128 m-tiles) x (4 heads).
// Wave w computes cols w*16..w*16+15 of the head for q,k,v via
// mfma_f32_16x16x32_bf16 (K=256 -> 8 steps, 24 MFMA/wave).
// A (e = exp(x-rowmax), bf16) staged in LDS in A-frag order
// (idx = ((kk*4+q)*16+m)*8+jj -> lane-consecutive 16B, conflict-free b128).
// Epilogue through LDS: remap to lane=col-in-head for the fused 64-wide
// softmax(q+k), log, bias, stores.
// ---------------------------------------------------------------------------
__global__ __launch_bounds__(256, 4) void qkv_mfma_kernel(
    const float* __restrict__ x,
    const unsigned short* __restrict__ EqS, const unsigned short* __restrict__ EkS,
    const unsigned short* __restrict__ EvS,
    const float* __restrict__ bq, const float* __restrict__ bk,
    const float* __restrict__ bv,
    float* __restrict__ attn, float* __restrict__ vout)
{
  int t = threadIdx.x;
  int w = t >> 6, lane = t & 63;
  int mt = blockIdx.x >> 2, h = blockIdx.x & 3;
  int row0 = mt * 16;

  __shared__ unsigned short aswz[8 * 512];   // 8 KB: [kk][q][m][jj]
  __shared__ float fbuf[3][16][65];          // ~12.5 KB (pad 65: no conflicts)
  __shared__ float Mrow[16];

  // --- prologue: wave w stages rows 4w..4w+3 as bf16 A-fragments ---
#pragma unroll
  for (int i = 0; i < 4; ++i) {
    int r = 4 * w + i;
    float4 xv = *(const float4*)&x[(size_t)(row0 + r) * ED + lane * 4];
    float m = fmaxf(fmaxf(xv.x, xv.y), fmaxf(xv.z, xv.w));
#pragma unroll
    for (int off = 32; off > 0; off >>= 1) m = fmaxf(m, __shfl_xor(m, off));
    ushort4 pk;
    pk.x = f2bf(__expf(xv.x - m));
    pk.y = f2bf(__expf(xv.y - m));
    pk.z = f2bf(__expf(xv.z - m));
    pk.w = f2bf(__expf(xv.w - m));
    int k0 = lane * 4;                         // kk=k0>>5, q=(k0>>3)&3, jj=k0&7
    int idx = (k0 >> 5) * 512 + ((k0 >> 3) & 3) * 128 + r * 8 + (k0 & 7);
    *(ushort4*)&aswz[idx] = pk;
    if (lane == 0) Mrow[r] = m;
  }
  __syncthreads();

  // --- A fragments: lane-consecutive 16B chunks ---
  short8 afrag[8];
#pragma unroll
  for (int kk = 0; kk < 8; ++kk)
    afrag[kk] = *(const short8*)&aswz[kk * 512 + lane * 8];

  // --- MFMA main loop: B frags straight from pre-swizzled global (L2) ---
  int bb = ((h * 64 + w * 16 + (lane & 15)) << 2) + (w >> 2, lane >> 4);
  bb = ((h * 64 + w * 16 + (lane & 15)) << 2) + (lane >> 4);
  const short8* BQ = (const short8*)EqS;
  const short8* BK = (const short8*)EkS;
  const short8* BV = (const short8*)EvS;
  floatx4 accq = {0.f, 0.f, 0.f, 0.f};
  floatx4 acck = {0.f, 0.f, 0.f, 0.f};
  floatx4 accv = {0.f, 0.f, 0.f, 0.f};
#pragma unroll
  for (int kk = 0; kk < 8; ++kk) {
    short8 bqf = BQ[kk * 1024 + bb];
    short8 bkf = BK[kk * 1024 + bb];
    short8 bvf = BV[kk * 1024 + bb];
    accq = __builtin_amdgcn_mfma_f32_16x16x32_bf16(afrag[kk], bqf, accq, 0, 0, 0);
    acck = __builtin_amdgcn_mfma_f32_16x16x32_bf16(afrag[kk], bkf, acck, 0, 0, 0);
    accv = __builtin_amdgcn_mfma_f32_16x16x32_bf16(afrag[kk], bvf, accv, 0, 0, 0);
  }

  // --- C frags -> LDS (D: col=lane&15, row=4*(lane>>4)+reg) ---
  {
    int c = w * 16 + (lane & 15);
    int rb = (lane >> 4) * 4;
#pragma unroll
    for (int reg = 0; reg < 4; ++reg) {
      fbuf[0][rb + reg][c] = accq[reg];
      fbuf[1][rb + reg][c] = acck[reg];
      fbuf[2][rb + reg][c] = accv[reg];
    }
  }
  __syncthreads();

  // --- epilogue: wave w owns rows 4w..4w+3, lane = col within head ---
  int cg = h * 64 + lane;
  float bqv = bq[cg], bkv = bk[cg], bvv = bv[cg];
#pragma unroll
  for (int i = 0; i < 4; ++i) {
    int r = 4 * w + i;
    float Mr = Mrow[r];
    float qv = Mr + __logf(fbuf[0][r][lane]) + bqv;
    float kv = Mr + __logf(fbuf[1][r][lane]) + bkv;
    float vv = Mr + __logf(fbuf[2][r][lane]) + bvv;
    vout[(size_t)(row0 + r) * ED + cg] = vv;
    float s = qv + kv;
    float sm = s;
#pragma unroll
    for (int off = 32; off > 0; off >>= 1) sm = fmaxf(sm, __shfl_xor(sm, off));
    float ex = __expf(s - sm);
    float den = ex;
#pragma unroll
    for (int off = 32; off > 0; off >>= 1) den += __shfl_xor(den, off);
    attn[(size_t)(row0 + r) * ED + cg] = ex / den;
  }
}

// ---------------------------------------------------------------------------
// Kernel C: fused attn@v + output tropical linear (unchanged from round 3).
// RB=4 rows/block, 512 blocks x 1024 threads.
// ---------------------------------------------------------------------------
__global__ __launch_bounds__(1024, 8) void avo_kernel(
    const float* __restrict__ attn, const float* __restrict__ vbuf,
    const unsigned short* __restrict__ EoT, const float* __restrict__ bo,
    float* __restrict__ y)
{
  int tid = threadIdx.x;
  int wv = tid >> 6, lane = tid & 63;
  int g = tid >> 8, t = tid & 255;
  int b = blockIdx.x >> 4;
  int row0 = b * SD + (blockIdx.x & 15) * RB;

  __shared__ float att[RB][ED];        // 4 KB
  __shared__ float part[RB][ED][4];    // 16 KB
  __shared__ float eoT[ED][RB];        // 4 KB
  __shared__ float red[RB][4];

  att[g][t] = attn[(size_t)(row0 + g) * ED + t];
  float vr[16];
#pragma unroll
  for (int d = 0; d < 16; ++d)
    vr[d] = vbuf[(size_t)(b * SD + 16 * g + d) * ED + t];
  __syncthreads();

  int h64 = (t >> 6) << 6;
  float acc[RB];
#pragma unroll
  for (int r = 0; r < RB; ++r) {
    const float4* ap = (const float4*)&att[r][h64 + 16 * g];  // broadcast
    float a = 0.f;
#pragma unroll
    for (int d4 = 0; d4 < 4; ++d4) {
      float4 a4 = ap[d4];
      a = fmaf(a4.x, vr[4 * d4 + 0], a);
      a = fmaf(a4.y, vr[4 * d4 + 1], a);
      a = fmaf(a4.z, vr[4 * d4 + 2], a);
      a = fmaf(a4.w, vr[4 * d4 + 3], a);
    }
    acc[r] = a;
  }
#pragma unroll
  for (int r = 0; r < RB; ++r) part[r][t][g] = acc[r];
  __syncthreads();

  float4 p4 = *(const float4*)part[g][t];
  float orow = (p4.x + p4.y) + (p4.z + p4.w);
  float m = orow;
#pragma unroll
  for (int off = 32; off > 0; off >>= 1) m = fmaxf(m, __shfl_xor(m, off));
  if (lane == 0) red[g][wv & 3] = m;
  __syncthreads();
  float M = fmaxf(fmaxf(red[g][0], red[g][1]), fmaxf(red[g][2], red[g][3]));
  eoT[t][g] = __expf(orow - M);
  __syncthreads();

  float acc2[RB] = {0, 0, 0, 0};
  const unsigned short* po = EoT + (size_t)(64 * g) * ED + t;
#pragma unroll 4
  for (int j = 0; j < 64; ++j) {
    float4 e4 = *(const float4*)eoT[64 * g + j];
    float wo = bf2f(po[j * ED]);
    acc2[0] = fmaf(wo, e4.x, acc2[0]);
    acc2[1] = fmaf(wo, e4.y, acc2[1]);
    acc2[2] = fmaf(wo, e4.z, acc2[2]);
    acc2[3] = fmaf(wo, e4.w, acc2[3]);
  }
  __syncthreads();   // part reuse
#pragma unroll
  for (int r = 0; r < RB; ++r) part[r][t][g] = acc2[r];
  __syncthreads();

  float4 f4 = *(const float4*)part[g][t];
  float f = (f4.x + f4.y) + (f4.z + f4.w);
  y[(size_t)(row0 + g) * ED + t] = M + __logf(f) + bo[t];
}

// ---------------------------------------------------------------------------
extern "C" void kernel_launch(void* const* d_in, const int* in_sizes, int n_in,
                              void* d_out, int out_size, void* d_ws, size_t ws_size,
                              hipStream_t stream) {
  const float* x  = (const float*)d_in[0];
  const float* Wq = (const float*)d_in[1];
  const float* bq = (const float*)d_in[2];
  const float* Wk = (const float*)d_in[3];
  const float* bk = (const float*)d_in[4];
  const float* Wv = (const float*)d_in[5];
  const float* bv = (const float*)d_in[6];
  const float* Wo = (const float*)d_in[7];
  const float* bo = (const float*)d_in[8];
  float* y = (float*)d_out;

  // ws layout (bytes): EqS 128K | EkS 128K | EvS 128K | EoT 128K | attn 2M | v 2M
  char* ws = (char*)d_ws;
  unsigned short* EqS = (unsigned short*)(ws);
  unsigned short* EkS = (unsigned short*)(ws + 131072);
  unsigned short* EvS = (unsigned short*)(ws + 262144);
  unsigned short* EoT = (unsigned short*)(ws + 393216);
  float* attn = (float*)(ws + 524288);
  float* vbuf = (float*)(ws + 524288 + (size_t)NROWS * ED * 4);

  expT_swz_kernel<<<dim3(32, 3), 256, 0, stream>>>(Wq, Wk, Wv, EqS, EkS, EvS);
  expT_o_kernel<<<dim3(8, 8), 256, 0, stream>>>(Wo, EoT);
  qkv_mfma_kernel<<<512, 256, 0, stream>>>(x, EqS, EkS, EvS, bq, bk, bv,
                                           attn, vbuf);
  avo_kernel<<<NROWS / RB, 1024, 0, stream>>>(attn, vbuf, EoT, bo, y);
}

// Round 5
// 88.766 us; speedup vs baseline: 1.5090x; 1.0820x over previous
//
#include <hip/hip_runtime.h>

// Problem dims (fixed by reference): B=32, S=64, E=256, H=4, D=64
constexpr int ED = 256;    // embedding dim
constexpr int SD = 64;     // seq len
constexpr int BD = 32;     // batch
constexpr int NROWS = BD * SD;  // 2048 rows of (E)

typedef _Float16 half8 __attribute__((ext_vector_type(8)));
typedef float floatx4 __attribute__((ext_vector_type(4)));

__device__ inline unsigned short f2h(float f) {   // fp32 -> fp16 bits (RNE)
  union { _Float16 h; unsigned short u; } c;
  c.h = (_Float16)f;
  return c.u;
}

// ---------------------------------------------------------------------------
// Kernel A: B-fragment-swizzled fp16 exp(W) for all 4 weight matrices.
// B[k][n] = exp(W[n][k]); frag layout for mfma_f32_16x16x32 (lane l:
// n = l&15, k = 32*kk + 8*(l>>4) + jj): ushort idx = (kk*256+n)*32 + q*8+jj.
// Thread t: n = bx*8 + (t>>5), kl = t&31 (= q*8+jj) -> coalesced writes.
// grid (32,4), block 256.
// ---------------------------------------------------------------------------
__global__ __launch_bounds__(256) void expT_swz_kernel(
    const float* __restrict__ Wq, const float* __restrict__ Wk,
    const float* __restrict__ Wv, const float* __restrict__ Wo,
    unsigned short* __restrict__ EqS, unsigned short* __restrict__ EkS,
    unsigned short* __restrict__ EvS, unsigned short* __restrict__ EoS)
{
  int z = blockIdx.y;
  const float* W = (z == 0) ? Wq : (z == 1) ? Wk : (z == 2) ? Wv : Wo;
  unsigned short* out = (z == 0) ? EqS : (z == 1) ? EkS : (z == 2) ? EvS : EoS;
  int t = threadIdx.x;
  int n = blockIdx.x * 8 + (t >> 5), kl = t & 31;
#pragma unroll
  for (int kk = 0; kk < 8; ++kk)
    out[(kk * 256 + n) * 32 + kl] = f2h(__expf(W[n * ED + 32 * kk + kl]));
}

// ---------------------------------------------------------------------------
// Kernel B: MFMA qkv. Block = 4 waves = M-tile 16 rows x one head (64 cols).
// grid 512 = 128 m-tiles x 4 heads. 24 MFMAs/wave (q,k,v x 8 K-steps).
// Epilogue: fused 64-wide softmax(q+k); writes attn in A-frag-swizzled fp16
// (AS) and v in B-frag-swizzled fp16 (VS) for the avo kernel.
// ---------------------------------------------------------------------------
__global__ __launch_bounds__(256, 4) void qkv_mfma_kernel(
    const float* __restrict__ x,
    const unsigned short* __restrict__ EqS, const unsigned short* __restrict__ EkS,
    const unsigned short* __restrict__ EvS,
    const float* __restrict__ bq, const float* __restrict__ bk,
    const float* __restrict__ bv,
    unsigned short* __restrict__ AS, unsigned short* __restrict__ VS)
{
  int t = threadIdx.x;
  int w = t >> 6, lane = t & 63;
  int mt = blockIdx.x >> 2, h = blockIdx.x & 3;
  int row0 = mt * 16;

  __shared__ unsigned short aswz[8 * 512];   // 8 KB fp16 A-frags [kk][q][m][jj]
  __shared__ float fbuf[3][16][65];          // ~12.5 KB (pad 65)
  __shared__ float Mrow[16];

  // --- prologue: wave w stages rows 4w..4w+3 as fp16 A-fragments ---
#pragma unroll
  for (int i = 0; i < 4; ++i) {
    int r = 4 * w + i;
    float4 xv = *(const float4*)&x[(size_t)(row0 + r) * ED + lane * 4];
    float m = fmaxf(fmaxf(xv.x, xv.y), fmaxf(xv.z, xv.w));
#pragma unroll
    for (int off = 32; off > 0; off >>= 1) m = fmaxf(m, __shfl_xor(m, off));
    ushort4 pk;
    pk.x = f2h(__expf(xv.x - m));
    pk.y = f2h(__expf(xv.y - m));
    pk.z = f2h(__expf(xv.z - m));
    pk.w = f2h(__expf(xv.w - m));
    int k0 = lane * 4;                       // kk=k0>>5, q=(k0>>3)&3, jj=k0&7
    int idx = (k0 >> 5) * 512 + ((k0 >> 3) & 3) * 128 + r * 8 + (k0 & 7);
    *(ushort4*)&aswz[idx] = pk;
    if (lane == 0) Mrow[r] = m;
  }
  __syncthreads();

  // --- A fragments: lane-consecutive 16B chunks, conflict-free b128 ---
  half8 afrag[8];
#pragma unroll
  for (int kk = 0; kk < 8; ++kk)
    afrag[kk] = *(const half8*)&aswz[kk * 512 + lane * 8];

  // --- MFMA main loop: B frags from pre-swizzled global (L2-resident) ---
  int bb = ((h * 64 + w * 16 + (lane & 15)) << 2) + (lane >> 4);
  const half8* BQ = (const half8*)EqS;
  const half8* BK = (const half8*)EkS;
  const half8* BV = (const half8*)EvS;
  floatx4 accq = {0.f, 0.f, 0.f, 0.f};
  floatx4 acck = {0.f, 0.f, 0.f, 0.f};
  floatx4 accv = {0.f, 0.f, 0.f, 0.f};
#pragma unroll
  for (int kk = 0; kk < 8; ++kk) {
    half8 bqf = BQ[kk * 1024 + bb];
    half8 bkf = BK[kk * 1024 + bb];
    half8 bvf = BV[kk * 1024 + bb];
    accq = __builtin_amdgcn_mfma_f32_16x16x32_f16(afrag[kk], bqf, accq, 0, 0, 0);
    acck = __builtin_amdgcn_mfma_f32_16x16x32_f16(afrag[kk], bkf, acck, 0, 0, 0);
    accv = __builtin_amdgcn_mfma_f32_16x16x32_f16(afrag[kk], bvf, accv, 0, 0, 0);
  }

  // --- C frags -> LDS (D: col=lane&15, row=4*(lane>>4)+reg) ---
  {
    int c = w * 16 + (lane & 15);
    int rb = (lane >> 4) * 4;
#pragma unroll
    for (int reg = 0; reg < 4; ++reg) {
      fbuf[0][rb + reg][c] = accq[reg];
      fbuf[1][rb + reg][c] = acck[reg];
      fbuf[2][rb + reg][c] = accv[reg];
    }
  }
  __syncthreads();

  // --- epilogue: wave w owns rows 4w..4w+3; lane = col (d) within head ---
  int cg = h * 64 + lane;
  float bqv = bq[cg], bkv = bk[cg], bvv = bv[cg];
  int b = row0 >> 6;
  int mt16 = (row0 >> 4) & 3;
  size_t asBase = (size_t)(((b * 4 + mt16) * 4) + h) * 1024
                + (lane >> 5) * 512 + ((lane >> 3) & 3) * 128 + (lane & 7);
#pragma unroll
  for (int i = 0; i < 4; ++i) {
    int r = 4 * w + i;
    float Mr = Mrow[r];
    float qv = Mr + __logf(fbuf[0][r][lane]) + bqv;
    float kv = Mr + __logf(fbuf[1][r][lane]) + bkv;
    float vv = Mr + __logf(fbuf[2][r][lane]) + bvv;
    // v -> B-frag-swizzled VS: k = d = mt16*16 + r, n = cg
    int d = mt16 * 16 + r;
    VS[(size_t)(b * 2 + (d >> 5)) * 8192 + cg * 32 + ((d >> 3) & 3) * 8 + (d & 7)]
        = f2h(vv);
    // softmax of q+k over the 64-lane head segment
    float s = qv + kv;
    float sm = s;
#pragma unroll
    for (int off = 32; off > 0; off >>= 1) sm = fmaxf(sm, __shfl_xor(sm, off));
    float ex = __expf(s - sm);
    float den = ex;
#pragma unroll
    for (int off = 32; off > 0; off >>= 1) den += __shfl_xor(den, off);
    // attn -> A-frag-swizzled AS: m = r, k = lane
    AS[asBase + r * 8] = f2h(ex / den);
  }
}

// ---------------------------------------------------------------------------
// Kernel C: fused MFMA attn@v + output tropical linear.
// grid 128 = (b,mt): block = 4 waves; wave w = head w for attn@v
// (M=16,N=64,K=64 -> 8 MFMAs), then o-linear (K=256 -> 32 MFMAs).
// ---------------------------------------------------------------------------
__global__ __launch_bounds__(256) void avo_mfma_kernel(
    const unsigned short* __restrict__ AS, const unsigned short* __restrict__ VS,
    const unsigned short* __restrict__ EoS, const float* __restrict__ bo,
    float* __restrict__ y)
{
  int t = threadIdx.x, w = t >> 6, lane = t & 63;
  int b = blockIdx.x >> 2, mt = blockIdx.x & 3;
  int row0 = b * 64 + mt * 16;
  int q = lane >> 4, nl = lane & 15;

  __shared__ float obuf[16][260];            // 16.6 KB (pad 260)
  __shared__ unsigned short easwz[8 * 512];  // 8 KB
  __shared__ float Mrow[16];

  // ---- attn@v: wave w = head w ----
  const half8* AS8 = (const half8*)(AS + (size_t)(((b * 4 + mt) * 4) + w) * 1024);
  const half8* VS8 = (const half8*)VS;
  half8 af0 = AS8[lane], af1 = AS8[64 + lane];
  floatx4 acc[4];
#pragma unroll
  for (int nt = 0; nt < 4; ++nt) acc[nt] = (floatx4){0.f, 0.f, 0.f, 0.f};
#pragma unroll
  for (int nt = 0; nt < 4; ++nt) {
    int n = w * 64 + nt * 16 + nl;
    half8 b0 = VS8[(size_t)(b * 2 + 0) * 1024 + n * 4 + q];
    half8 b1 = VS8[(size_t)(b * 2 + 1) * 1024 + n * 4 + q];
    acc[nt] = __builtin_amdgcn_mfma_f32_16x16x32_f16(af0, b0, acc[nt], 0, 0, 0);
    acc[nt] = __builtin_amdgcn_mfma_f32_16x16x32_f16(af1, b1, acc[nt], 0, 0, 0);
  }
  int rb = q * 4;
#pragma unroll
  for (int nt = 0; nt < 4; ++nt)
#pragma unroll
    for (int reg = 0; reg < 4; ++reg)
      obuf[rb + reg][w * 64 + nt * 16 + nl] = acc[nt][reg];
  __syncthreads();

  // ---- rowmax + exp + A-frag swizzle for the o-linear ----
#pragma unroll
  for (int i = 0; i < 4; ++i) {
    int r = 4 * w + i;
    float4 o4 = *(const float4*)&obuf[r][lane * 4];
    float m = fmaxf(fmaxf(o4.x, o4.y), fmaxf(o4.z, o4.w));
#pragma unroll
    for (int off = 32; off > 0; off >>= 1) m = fmaxf(m, __shfl_xor(m, off));
    ushort4 pk;
    pk.x = f2h(__expf(o4.x - m));
    pk.y = f2h(__expf(o4.y - m));
    pk.z = f2h(__expf(o4.z - m));
    pk.w = f2h(__expf(o4.w - m));
    int k0 = lane * 4;
    int idx = (k0 >> 5) * 512 + ((k0 >> 3) & 3) * 128 + r * 8 + (k0 & 7);
    *(ushort4*)&easwz[idx] = pk;
    if (lane == 0) Mrow[r] = m;
  }
  __syncthreads();

  // ---- o-linear MFMA: wave w covers cols w*64..w*64+63 ----
  half8 af2[8];
#pragma unroll
  for (int kk = 0; kk < 8; ++kk)
    af2[kk] = *(const half8*)&easwz[kk * 512 + lane * 8];
  const half8* BO = (const half8*)EoS;
  floatx4 acc2[4];
#pragma unroll
  for (int nt = 0; nt < 4; ++nt) acc2[nt] = (floatx4){0.f, 0.f, 0.f, 0.f};
#pragma unroll
  for (int kk = 0; kk < 8; ++kk) {
#pragma unroll
    for (int nt = 0; nt < 4; ++nt) {
      int n = w * 64 + nt * 16 + nl;
      acc2[nt] = __builtin_amdgcn_mfma_f32_16x16x32_f16(
          af2[kk], BO[kk * 1024 + n * 4 + q], acc2[nt], 0, 0, 0);
    }
  }
#pragma unroll
  for (int nt = 0; nt < 4; ++nt)
#pragma unroll
    for (int reg = 0; reg < 4; ++reg)
      obuf[rb + reg][w * 64 + nt * 16 + nl] = acc2[nt][reg];
  __syncthreads();

  // ---- epilogue: log + bias, coalesced float4 stores ----
  float4 bo4 = *(const float4*)&bo[lane * 4];
#pragma unroll
  for (int i = 0; i < 4; ++i) {
    int r = 4 * w + i;
    float4 f4 = *(const float4*)&obuf[r][lane * 4];
    float M = Mrow[r];
    float4 y4;
    y4.x = M + __logf(f4.x) + bo4.x;
    y4.y = M + __logf(f4.y) + bo4.y;
    y4.z = M + __logf(f4.z) + bo4.z;
    y4.w = M + __logf(f4.w) + bo4.w;
    *(float4*)&y[(size_t)(row0 + r) * ED + lane * 4] = y4;
  }
}

// ---------------------------------------------------------------------------
extern "C" void kernel_launch(void* const* d_in, const int* in_sizes, int n_in,
                              void* d_out, int out_size, void* d_ws, size_t ws_size,
                              hipStream_t stream) {
  const float* x  = (const float*)d_in[0];
  const float* Wq = (const float*)d_in[1];
  const float* bq = (const float*)d_in[2];
  const float* Wk = (const float*)d_in[3];
  const float* bk = (const float*)d_in[4];
  const float* Wv = (const float*)d_in[5];
  const float* bv = (const float*)d_in[6];
  const float* Wo = (const float*)d_in[7];
  const float* bo = (const float*)d_in[8];
  float* y = (float*)d_out;

  // ws (bytes): EqS/EkS/EvS/EoS 128K each | AS 1M | VS 1M  (total 2.5 MB)
  char* ws = (char*)d_ws;
  unsigned short* EqS = (unsigned short*)(ws);
  unsigned short* EkS = (unsigned short*)(ws + 131072);
  unsigned short* EvS = (unsigned short*)(ws + 262144);
  unsigned short* EoS = (unsigned short*)(ws + 393216);
  unsigned short* AS  = (unsigned short*)(ws + 524288);
  unsigned short* VS  = (unsigned short*)(ws + 524288 + 1048576);

  expT_swz_kernel<<<dim3(32, 4), 256, 0, stream>>>(Wq, Wk, Wv, Wo,
                                                   EqS, EkS, EvS, EoS);
  qkv_mfma_kernel<<<512, 256, 0, stream>>>(x, EqS, EkS, EvS, bq, bk, bv,
                                           AS, VS);
  avo_mfma_kernel<<<128, 256, 0, stream>>>(AS, VS, EoS, bo, y);
}

// Round 6
// 86.693 us; speedup vs baseline: 1.5451x; 1.0239x over previous
//
#include <hip/hip_runtime.h>

// Problem dims (fixed by reference): B=32, S=64, E=256, H=4, D=64
constexpr int ED = 256;    // embedding dim
constexpr int SD = 64;     // seq len
constexpr int BD = 32;     // batch
constexpr int NROWS = BD * SD;  // 2048 rows of (E)

typedef _Float16 half8 __attribute__((ext_vector_type(8)));
typedef float floatx4 __attribute__((ext_vector_type(4)));

__device__ inline unsigned short f2h(float f) {   // fp32 -> fp16 bits (RNE)
  union { _Float16 h; unsigned short u; } c;
  c.h = (_Float16)f;
  return c.u;
}

// ---------------------------------------------------------------------------
// Kernel A: B-fragment-swizzled fp16 exp(W) for all 4 weight matrices.
// B[k][n] = exp(W[n][k]); frag layout for mfma_f32_16x16x32 (lane l:
// n = l&15, k = 32*kk + 8*(l>>4) + jj): ushort idx = (kk*256+n)*32 + q*8+jj.
// grid (32,4), block 256.
// ---------------------------------------------------------------------------
__global__ __launch_bounds__(256) void expT_swz_kernel(
    const float* __restrict__ Wq, const float* __restrict__ Wk,
    const float* __restrict__ Wv, const float* __restrict__ Wo,
    unsigned short* __restrict__ EqS, unsigned short* __restrict__ EkS,
    unsigned short* __restrict__ EvS, unsigned short* __restrict__ EoS)
{
  int z = blockIdx.y;
  const float* W = (z == 0) ? Wq : (z == 1) ? Wk : (z == 2) ? Wv : Wo;
  unsigned short* out = (z == 0) ? EqS : (z == 1) ? EkS : (z == 2) ? EvS : EoS;
  int t = threadIdx.x;
  int n = blockIdx.x * 8 + (t >> 5), kl = t & 31;
#pragma unroll
  for (int kk = 0; kk < 8; ++kk)
    out[(kk * 256 + n) * 32 + kl] = f2h(__expf(W[n * ED + 32 * kk + kl]));
}

// ---------------------------------------------------------------------------
// Kernel B: MFMA qkv. Block = 4 waves = M-tile 16 rows x one head (64 cols).
// grid 512 = 128 m-tiles x 4 heads (2 blocks/CU). launch_bounds(256,2):
// lets the 24 B-fragments + 4 x-rows be loaded into registers UP FRONT
// (~112 VGPRs) so L2 latency overlaps the exp/shuffle prologue.
// Epilogue: fused 64-wide softmax(q+k); writes attn in A-frag-swizzled fp16
// (AS) and v in B-frag-swizzled fp16 (VS).
// ---------------------------------------------------------------------------
__global__ __launch_bounds__(256, 2) void qkv_mfma_kernel(
    const float* __restrict__ x,
    const unsigned short* __restrict__ EqS, const unsigned short* __restrict__ EkS,
    const unsigned short* __restrict__ EvS,
    const float* __restrict__ bq, const float* __restrict__ bk,
    const float* __restrict__ bv,
    unsigned short* __restrict__ AS, unsigned short* __restrict__ VS)
{
  int t = threadIdx.x;
  int w = t >> 6, lane = t & 63;
  int mt = blockIdx.x >> 2, h = blockIdx.x & 3;
  int row0 = mt * 16;

  __shared__ unsigned short aswz[8 * 512];   // 8 KB fp16 A-frags [kk][q][m][jj]
  __shared__ float fbuf[3][16][65];          // ~12.5 KB (pad 65)
  __shared__ float Mrow[16];

  // --- issue ALL global loads first: 4 x-rows + 24 B-fragments ---
  float4 xv[4];
#pragma unroll
  for (int i = 0; i < 4; ++i)
    xv[i] = *(const float4*)&x[(size_t)(row0 + 4 * w + i) * ED + lane * 4];

  int bb = ((h * 64 + w * 16 + (lane & 15)) << 2) + (lane >> 4);
  const half8* BQ = (const half8*)EqS;
  const half8* BK = (const half8*)EkS;
  const half8* BV = (const half8*)EvS;
  half8 bqf[8], bkf[8], bvf[8];
#pragma unroll
  for (int kk = 0; kk < 8; ++kk) {
    bqf[kk] = BQ[kk * 1024 + bb];
    bkf[kk] = BK[kk * 1024 + bb];
    bvf[kk] = BV[kk * 1024 + bb];
  }

  // --- prologue: wave w stages rows 4w..4w+3 as fp16 A-fragments ---
#pragma unroll
  for (int i = 0; i < 4; ++i) {
    int r = 4 * w + i;
    float m = fmaxf(fmaxf(xv[i].x, xv[i].y), fmaxf(xv[i].z, xv[i].w));
#pragma unroll
    for (int off = 32; off > 0; off >>= 1) m = fmaxf(m, __shfl_xor(m, off));
    ushort4 pk;
    pk.x = f2h(__expf(xv[i].x - m));
    pk.y = f2h(__expf(xv[i].y - m));
    pk.z = f2h(__expf(xv[i].z - m));
    pk.w = f2h(__expf(xv[i].w - m));
    int k0 = lane * 4;                       // kk=k0>>5, q=(k0>>3)&3, jj=k0&7
    int idx = (k0 >> 5) * 512 + ((k0 >> 3) & 3) * 128 + r * 8 + (k0 & 7);
    *(ushort4*)&aswz[idx] = pk;
    if (lane == 0) Mrow[r] = m;
  }
  __syncthreads();

  // --- A fragments: lane-consecutive 16B chunks, conflict-free b128 ---
  half8 afrag[8];
#pragma unroll
  for (int kk = 0; kk < 8; ++kk)
    afrag[kk] = *(const half8*)&aswz[kk * 512 + lane * 8];

  // --- MFMA main loop: B frags already in registers ---
  floatx4 accq = {0.f, 0.f, 0.f, 0.f};
  floatx4 acck = {0.f, 0.f, 0.f, 0.f};
  floatx4 accv = {0.f, 0.f, 0.f, 0.f};
#pragma unroll
  for (int kk = 0; kk < 8; ++kk) {
    accq = __builtin_amdgcn_mfma_f32_16x16x32_f16(afrag[kk], bqf[kk], accq, 0, 0, 0);
    acck = __builtin_amdgcn_mfma_f32_16x16x32_f16(afrag[kk], bkf[kk], acck, 0, 0, 0);
    accv = __builtin_amdgcn_mfma_f32_16x16x32_f16(afrag[kk], bvf[kk], accv, 0, 0, 0);
  }

  // --- C frags -> LDS (D: col=lane&15, row=4*(lane>>4)+reg) ---
  {
    int c = w * 16 + (lane & 15);
    int rb = (lane >> 4) * 4;
#pragma unroll
    for (int reg = 0; reg < 4; ++reg) {
      fbuf[0][rb + reg][c] = accq[reg];
      fbuf[1][rb + reg][c] = acck[reg];
      fbuf[2][rb + reg][c] = accv[reg];
    }
  }
  __syncthreads();

  // --- epilogue: wave w owns rows 4w..4w+3; lane = col (d) within head ---
  int cg = h * 64 + lane;
  float bqv = bq[cg], bkv = bk[cg], bvv = bv[cg];
  int b = row0 >> 6;
  int mt16 = (row0 >> 4) & 3;
  size_t asBase = (size_t)(((b * 4 + mt16) * 4) + h) * 1024
                + (lane >> 5) * 512 + ((lane >> 3) & 3) * 128 + (lane & 7);
#pragma unroll
  for (int i = 0; i < 4; ++i) {
    int r = 4 * w + i;
    float Mr = Mrow[r];
    float qv = Mr + __logf(fbuf[0][r][lane]) + bqv;
    float kv = Mr + __logf(fbuf[1][r][lane]) + bkv;
    float vv = Mr + __logf(fbuf[2][r][lane]) + bvv;
    // v -> B-frag-swizzled VS: k = d = mt16*16 + r, n = cg
    int d = mt16 * 16 + r;
    VS[(size_t)(b * 2 + (d >> 5)) * 8192 + cg * 32 + ((d >> 3) & 3) * 8 + (d & 7)]
        = f2h(vv);
    // softmax of q+k over the 64-lane head segment
    float s = qv + kv;
    float sm = s;
#pragma unroll
    for (int off = 32; off > 0; off >>= 1) sm = fmaxf(sm, __shfl_xor(sm, off));
    float ex = __expf(s - sm);
    float den = ex;
#pragma unroll
    for (int off = 32; off > 0; off >>= 1) den += __shfl_xor(den, off);
    // attn -> A-frag-swizzled AS: m = r, k = lane
    AS[asBase + r * 8] = f2h(ex / den);
  }
}

// ---------------------------------------------------------------------------
// Kernel C: fused MFMA attn@v + output tropical linear.
// grid 256 = (b, mt, half): block = 4 waves. Each block does the FULL
// attn@v (wave w = head w, 8 MFMAs — duplicated across the 2 halves) and
// full rowmax/exp, then the o-linear for its 128-col half only
// (16 MFMAs/wave instead of 32). Doubles CU coverage, shortens the chain.
// ---------------------------------------------------------------------------
__global__ __launch_bounds__(256, 2) void avo_mfma_kernel(
    const unsigned short* __restrict__ AS, const unsigned short* __restrict__ VS,
    const unsigned short* __restrict__ EoS, const float* __restrict__ bo,
    float* __restrict__ y)
{
  int t = threadIdx.x, w = t >> 6, lane = t & 63;
  int blk = blockIdx.x;
  int b = blk >> 3, mt = (blk >> 1) & 3, hf = blk & 1;
  int row0 = b * 64 + mt * 16;
  int q = lane >> 4, nl = lane & 15;

  __shared__ float obuf[16][260];            // 16.6 KB (pad 260)
  __shared__ unsigned short easwz[8 * 512];  // 8 KB
  __shared__ float Mrow[16];

  // ---- attn@v (full 256 cols): wave w = head w ----
  const half8* AS8 = (const half8*)(AS + (size_t)(((b * 4 + mt) * 4) + w) * 1024);
  const half8* VS8 = (const half8*)VS;
  half8 af0 = AS8[lane], af1 = AS8[64 + lane];
  floatx4 acc[4];
#pragma unroll
  for (int nt = 0; nt < 4; ++nt) acc[nt] = (floatx4){0.f, 0.f, 0.f, 0.f};
#pragma unroll
  for (int nt = 0; nt < 4; ++nt) {
    int n = w * 64 + nt * 16 + nl;
    half8 b0 = VS8[(size_t)(b * 2 + 0) * 1024 + n * 4 + q];
    half8 b1 = VS8[(size_t)(b * 2 + 1) * 1024 + n * 4 + q];
    acc[nt] = __builtin_amdgcn_mfma_f32_16x16x32_f16(af0, b0, acc[nt], 0, 0, 0);
    acc[nt] = __builtin_amdgcn_mfma_f32_16x16x32_f16(af1, b1, acc[nt], 0, 0, 0);
  }
  int rb = q * 4;
#pragma unroll
  for (int nt = 0; nt < 4; ++nt)
#pragma unroll
    for (int reg = 0; reg < 4; ++reg)
      obuf[rb + reg][w * 64 + nt * 16 + nl] = acc[nt][reg];
  __syncthreads();

  // ---- rowmax + exp + A-frag swizzle for the o-linear (full row) ----
#pragma unroll
  for (int i = 0; i < 4; ++i) {
    int r = 4 * w + i;
    float4 o4 = *(const float4*)&obuf[r][lane * 4];
    float m = fmaxf(fmaxf(o4.x, o4.y), fmaxf(o4.z, o4.w));
#pragma unroll
    for (int off = 32; off > 0; off >>= 1) m = fmaxf(m, __shfl_xor(m, off));
    ushort4 pk;
    pk.x = f2h(__expf(o4.x - m));
    pk.y = f2h(__expf(o4.y - m));
    pk.z = f2h(__expf(o4.z - m));
    pk.w = f2h(__expf(o4.w - m));
    int k0 = lane * 4;
    int idx = (k0 >> 5) * 512 + ((k0 >> 3) & 3) * 128 + r * 8 + (k0 & 7);
    *(ushort4*)&easwz[idx] = pk;
    if (lane == 0) Mrow[r] = m;
  }
  __syncthreads();

  // ---- o-linear MFMA: this half's 128 cols; wave w -> 32 cols ----
  half8 af2[8];
#pragma unroll
  for (int kk = 0; kk < 8; ++kk)
    af2[kk] = *(const half8*)&easwz[kk * 512 + lane * 8];
  const half8* BO = (const half8*)EoS;
  floatx4 acc2[2];
  acc2[0] = (floatx4){0.f, 0.f, 0.f, 0.f};
  acc2[1] = (floatx4){0.f, 0.f, 0.f, 0.f};
#pragma unroll
  for (int kk = 0; kk < 8; ++kk) {
#pragma unroll
    for (int nt = 0; nt < 2; ++nt) {
      int n = hf * 128 + w * 32 + nt * 16 + nl;
      acc2[nt] = __builtin_amdgcn_mfma_f32_16x16x32_f16(
          af2[kk], BO[kk * 1024 + n * 4 + q], acc2[nt], 0, 0, 0);
    }
  }
#pragma unroll
  for (int nt = 0; nt < 2; ++nt)
#pragma unroll
    for (int reg = 0; reg < 4; ++reg)
      obuf[rb + reg][hf * 128 + w * 32 + nt * 16 + nl] = acc2[nt][reg];
  __syncthreads();

  // ---- epilogue: log + bias, float2 stores over this half's 128 cols ----
  int c0 = hf * 128 + lane * 2;
  float2 bo2 = *(const float2*)&bo[c0];
#pragma unroll
  for (int i = 0; i < 4; ++i) {
    int r = 4 * w + i;
    float2 f2 = *(const float2*)&obuf[r][c0];
    float M = Mrow[r];
    float2 y2;
    y2.x = M + __logf(f2.x) + bo2.x;
    y2.y = M + __logf(f2.y) + bo2.y;
    *(float2*)&y[(size_t)(row0 + r) * ED + c0] = y2;
  }
}

// ---------------------------------------------------------------------------
extern "C" void kernel_launch(void* const* d_in, const int* in_sizes, int n_in,
                              void* d_out, int out_size, void* d_ws, size_t ws_size,
                              hipStream_t stream) {
  const float* x  = (const float*)d_in[0];
  const float* Wq = (const float*)d_in[1];
  const float* bq = (const float*)d_in[2];
  const float* Wk = (const float*)d_in[3];
  const float* bk = (const float*)d_in[4];
  const float* Wv = (const float*)d_in[5];
  const float* bv = (const float*)d_in[6];
  const float* Wo = (const float*)d_in[7];
  const float* bo = (const float*)d_in[8];
  float* y = (float*)d_out;

  // ws (bytes): EqS/EkS/EvS/EoS 128K each | AS 1M | VS 1M  (total 2.5 MB)
  char* ws = (char*)d_ws;
  unsigned short* EqS = (unsigned short*)(ws);
  unsigned short* EkS = (unsigned short*)(ws + 131072);
  unsigned short* EvS = (unsigned short*)(ws + 262144);
  unsigned short* EoS = (unsigned short*)(ws + 393216);
  unsigned short* AS  = (unsigned short*)(ws + 524288);
  unsigned short* VS  = (unsigned short*)(ws + 524288 + 1048576);

  expT_swz_kernel<<<dim3(32, 4), 256, 0, stream>>>(Wq, Wk, Wv, Wo,
                                                   EqS, EkS, EvS, EoS);
  qkv_mfma_kernel<<<512, 256, 0, stream>>>(x, EqS, EkS, EvS, bq, bk, bv,
                                           AS, VS);
  avo_mfma_kernel<<<256, 256, 0, stream>>>(AS, VS, EoS, bo, y);
}